// Round 15
// baseline (1113.445 us; speedup 1.0000x reference)
//
#include <hip/hip_runtime.h>

// ---------------------------------------------------------------------------
// EGNN scoring model, MI355X (gfx950).
// R14: (a) edge_v8 — MFMA edge kernel. R13 proved the edge op is L1-BW-bound
// on shared-weight re-reads; v8 moves weights to LDS frags (40KB, half-
// resident) and the h-dot + z-reduction onto the matrix pipe. Per wave =
// 16 edges; z in one f32x4 accumulator; C1-MFMA C/D layout provably matches
// the z-MFMA A-layout (same mapping as the R12-proven gemm_kernel).
// (b) gemm1 xs=1 -> xs=2: R13 absmax 0.0078125 was 1 display-ULP from the
// 0.00785 threshold; feats hi/lo split restores margin.
// ---------------------------------------------------------------------------

typedef unsigned int u32;
typedef unsigned long long u64;
typedef float f32x4 __attribute__((ext_vector_type(4)));
typedef __bf16 bf16x4 __attribute__((ext_vector_type(4)));
typedef __bf16 bf16x8 __attribute__((ext_vector_type(8)));

#define NB 16
#define NN 2048
#define DD 142
#define KNNK 10
#define NNODES (NB * NN)        // 32768
#define NEDGES (NNODES * KNNK)  // 327680
#define E1OUT 610
#define APITCH 640

__device__ __forceinline__ f32x4 mfma16(bf16x8 a, bf16x8 b, f32x4 c) {
  return __builtin_amdgcn_mfma_f32_16x16x32_bf16(a, b, c, 0, 0, 0);
}
__device__ __forceinline__ float siluf(float x) { return x / (1.0f + __expf(-x)); }

__device__ __forceinline__ u64 wave_min_u64(u64 v) {
#pragma unroll
  for (int off = 32; off >= 1; off >>= 1) {
    u32 lo = (u32)v, hi = (u32)(v >> 32);
    u32 olo = (u32)__shfl_xor((int)lo, off, 64);
    u32 ohi = (u32)__shfl_xor((int)hi, off, 64);
    u64 o = ((u64)ohi << 32) | (u64)olo;
    v = (o < v) ? o : v;
  }
  return v;
}

__device__ __forceinline__ bf16x8 ldfrag40(const __bf16* p) {
  bf16x4 lo = *(const bf16x4*)p;
  bf16x4 hi = *(const bf16x4*)(p + 16);
  return __builtin_shufflevector(lo, hi, 0, 1, 2, 3, 4, 5, 6, 7);
}

// ---------------------------------------------------------------------------
// Wave-parallel KNN (proven, unchanged).
// ---------------------------------------------------------------------------
__global__ __launch_bounds__(256) void knn_kernel(const float* __restrict__ coors,
                                                  int* __restrict__ idxo,
                                                  float* __restrict__ disto) {
  __shared__ float cl[NN * 3];
  int b = blockIdx.x >> 9;
  int i0 = (blockIdx.x & 511) << 2;
  for (int t = threadIdx.x; t < NN * 3; t += 256) cl[t] = coors[b * NN * 3 + t];
  __syncthreads();
  int wave = threadIdx.x >> 6, lane = threadIdx.x & 63;
  int il = i0 + wave;
  float xi = cl[il * 3 + 0], yi = cl[il * 3 + 1], zi = cl[il * 3 + 2];
  u64 r[KNNK];
#pragma unroll
  for (int t = 0; t < KNNK; ++t) r[t] = ~0ull;
  for (int j0 = 0; j0 < NN; j0 += 64) {
    int j = j0 + lane;
    float dx = __fadd_rn(xi, -cl[j * 3 + 0]);
    float dy = __fadd_rn(yi, -cl[j * 3 + 1]);
    float dz = __fadd_rn(zi, -cl[j * 3 + 2]);
    float d2 = __fadd_rn(__fadd_rn(__fmul_rn(dx, dx), __fmul_rn(dy, dy)), __fmul_rn(dz, dz));
    u64 cand = ((u64)__float_as_uint(d2) << 32) | (u64)(u32)j;
    if (cand < r[KNNK - 1]) {
      r[KNNK - 1] = cand;
#pragma unroll
      for (int t = KNNK - 1; t > 0; --t) {
        if (r[t] < r[t - 1]) { u64 tmp = r[t - 1]; r[t - 1] = r[t]; r[t] = tmp; }
      }
    }
  }
  int gi = b * NN + il;
#pragma unroll
  for (int t = 0; t < KNNK; ++t) {
    u64 head = r[0];
    u64 m = wave_min_u64(head);
    if (lane == t) {
      idxo[(size_t)gi * KNNK + t] = b * NN + (int)(u32)(m & 0xffffffffu);
      disto[(size_t)gi * KNNK + t] = __uint_as_float((u32)(m >> 32));
    }
    if (head == m) {
#pragma unroll
      for (int q = 0; q < KNNK - 1; ++q) r[q] = r[q + 1];
      r[KNNK - 1] = ~0ull;
    }
  }
}

// ---------------------------------------------------------------------------
// bf16-MFMA GEMM (proven R12; now xs=2 for feats hi/lo margin).
// ---------------------------------------------------------------------------
__global__ __launch_bounds__(256) void gemm_kernel(
    const float* __restrict__ X, int ldx, int K,
    const float* __restrict__ W, int ldw, int r0, int Ncols,
    const float* __restrict__ bias, const float* __restrict__ resid, int ldr,
    float* __restrict__ C, int ldc, int doSilu, int xs, int ws) {
  __shared__ __bf16 Xs[2][64 * 40];
  __shared__ __bf16 Ws[2][64 * 40];
  int m0 = blockIdx.y * 64, n0 = blockIdx.x * 64;
  int tid = threadIdx.x;
  int lane = tid & 63, wv = tid >> 6;
  int g = lane >> 4, rr = lane & 15;
  f32x4 acc[4];
#pragma unroll
  for (int ct = 0; ct < 4; ++ct) acc[ct] = (f32x4){0.f, 0.f, 0.f, 0.f};
  int nk = (K + 31) >> 5;
  int rs = tid >> 2, q = tid & 3;
  for (int kc = 0; kc < nk; ++kc) {
    int k0 = kc << 5;
#pragma unroll
    for (int u = 0; u < 8; ++u) {
      int kk = q * 8 + u;
      int k = k0 + kk;
      float xv = (k < K) ? X[(size_t)(m0 + rs) * ldx + k] : 0.0f;
      __bf16 xh = (__bf16)xv;
      Xs[0][rs * 40 + kk] = xh;
      if (xs == 2) Xs[1][rs * 40 + kk] = (__bf16)(xv - (float)xh);
      float wvv = (k < K && (n0 + rs) < Ncols) ? W[(size_t)(r0 + k) * ldw + n0 + rs] : 0.0f;
      __bf16 wh = (__bf16)wvv;
      Ws[0][rs * 40 + kk] = wh;
      if (ws == 2) Ws[1][rs * 40 + kk] = (__bf16)(wvv - (float)wh);
    }
    __syncthreads();
    for (int ix = 0; ix < xs; ++ix) {
      bf16x8 a = ldfrag40(&Xs[ix][(16 * wv + rr) * 40 + 4 * g]);
      for (int iw = 0; iw < ws; ++iw) {
#pragma unroll
        for (int ct = 0; ct < 4; ++ct) {
          bf16x8 bb = ldfrag40(&Ws[iw][(16 * ct + rr) * 40 + 4 * g]);
          acc[ct] = mfma16(a, bb, acc[ct]);
        }
      }
    }
    __syncthreads();
  }
#pragma unroll
  for (int ct = 0; ct < 4; ++ct) {
#pragma unroll
    for (int r = 0; r < 4; ++r) {
      int row = m0 + 16 * wv + 4 * g + r;
      int col = n0 + 16 * ct + rr;
      if (col < Ncols) {
        float v = acc[ct][r];
        if (bias) v += bias[col];
        if (doSilu) v = siluf(v);
        if (resid) v += resid[(size_t)row * ldr + col];
        C[(size_t)row * ldc + col] = v;
      }
    }
  }
}

// ---------------------------------------------------------------------------
// Brute linear (proven; node MLP).
// ---------------------------------------------------------------------------
__global__ __launch_bounds__(256) void brute_lin(
    const float* __restrict__ X, int ldx, int K,
    const float* __restrict__ W, int ldw, int r0, int Ncols,
    const float* __restrict__ bias, const float* __restrict__ resid, int ldr,
    float* __restrict__ Y, int ldy, int doSilu) {
  __shared__ float Xs[8 * 284];
  int n0 = blockIdx.x * 8;
  int tid = threadIdx.x;
  for (int p = tid; p < 8 * K; p += 256) {
    int n = p / K, k = p - n * K;
    Xs[n * K + k] = X[(size_t)(n0 + n) * ldx + k];
  }
  __syncthreads();
  float acc[8][3];
#pragma unroll
  for (int n = 0; n < 8; ++n)
#pragma unroll
    for (int s = 0; s < 3; ++s) acc[n][s] = 0.0f;
  int e1 = tid + 256, e2 = tid + 512;
  for (int k = 0; k < K; ++k) {
    const float* wr = W + (size_t)(r0 + k) * ldw;
    float w0 = (tid < Ncols) ? wr[tid] : 0.0f;
    float w1 = (e1 < Ncols) ? wr[e1] : 0.0f;
    float w2 = (e2 < Ncols) ? wr[e2] : 0.0f;
#pragma unroll
    for (int n = 0; n < 8; ++n) {
      float xv = Xs[n * K + k];
      acc[n][0] += xv * w0;
      acc[n][1] += xv * w1;
      acc[n][2] += xv * w2;
    }
  }
#pragma unroll
  for (int n = 0; n < 8; ++n) {
#pragma unroll
    for (int s = 0; s < 3; ++s) {
      int e = tid + s * 256;
      if (e < Ncols) {
        float v = acc[n][s];
        if (bias) v += bias[e];
        if (doSilu) v = siluf(v);
        if (resid) v += resid[(size_t)(n0 + n) * ldr + e];
        Y[(size_t)(n0 + n) * ldy + e] = v;
      }
    }
  }
}

// ---------------------------------------------------------------------------
// Edge kernel v8 (MFMA). 1024 threads = 16 waves; each wave owns 16 edges.
// LDS: pre-swizzled WdT A-frags + W_e2 hi/lo B-frags, half-resident (40KB).
// Per 32-e chunk: S = Ap+Bm gather (4x float4); C1 = WdT@DF (2 MFMA, C/D
// layout == S layout == next A layout); h=S+C1; silu -> a2 frag;
// z += a2 @ W_e2 (hi+lo MFMA). Epilogue: silu(z+b) -> 4 atomics/lane.
// ---------------------------------------------------------------------------
struct EdgeV8Lds {
  __bf16 A1F[20 * 512];   // WdT frags for current half: (cpl*2+sb)*512 + l*8+s
  __bf16 W2Fh[10 * 512];  // W_e2 hi frags
  __bf16 W2Fl[10 * 512];  // W_e2 lo frags
};  // 40960 B

__global__ __launch_bounds__(1024) void edge_v8(
    const float* __restrict__ Ap, const float* __restrict__ Bmm,
    const int* __restrict__ idxE, const float* __restrict__ distE,
    const float* __restrict__ W_e1, const float* __restrict__ W_e2,
    const float* __restrict__ b_e2, float* __restrict__ m_i) {
  __shared__ EdgeV8Lds L;
  int tid = threadIdx.x;
  int wave = tid >> 6, lane = tid & 63;
  int g = lane >> 4, er = lane & 15;
  int tile = blockIdx.x * 16 + wave;  // 1280 blocks * 16 waves = 20480 tiles
  int Ebase = tile * 16;

  // meta for this lane's frag edge (er)
  int Ee = Ebase + er;
  int iE = Ee / 10;
  int jE = idxE[Ee];
  float d2 = distE[Ee];

  // df B-frag: slot s -> t = s<4 ? 4g+s : 16+4g+(s-4); same t<->row map as
  // the proven edge kernels (sin rows 284.., cos 294.., raw 304).
  bf16x8 dfB;
#pragma unroll
  for (int s = 0; s < 8; ++s) {
    int t = (s < 4) ? (4 * g + s) : (16 + 4 * g + (s - 4));
    float v = 0.0f;
    if (t < 10) v = sinf(d2 / (float)(1 << t));
    else if (t < 20) v = cosf(d2 / (float)(1 << (t - 10)));
    else if (t == 20) v = d2;
    dfB[s] = (__bf16)v;
  }

  const float* arow = Ap + (size_t)iE * APITCH;
  const float* brow = Bmm + (size_t)jE * APITCH;

  f32x4 zacc = {0.f, 0.f, 0.f, 0.f};
  f32x4 zero4 = {0.f, 0.f, 0.f, 0.f};

#pragma unroll 1
  for (int hh = 0; hh < 2; ++hh) {
    if (hh) __syncthreads();  // all waves done reading previous half
    // ---- prep A1F: WdT[e][t] frags; A[row=e_local=l&15][k=t] ----
    for (int it = 0; it < 10; ++it) {
      int idx = it * 1024 + tid;  // 0..10239
      int s = idx & 7, l = (idx >> 3) & 63, fid = idx >> 9;  // fid 0..19
      int gg = l >> 4;
      int t = (s < 4) ? (4 * gg + s) : (16 + 4 * gg + (s - 4));
      int e = (hh * 10 + (fid >> 1)) * 32 + (fid & 1) * 16 + (l & 15);
      float v = (t < 21 && e < E1OUT) ? W_e1[(284 + t) * E1OUT + e] : 0.0f;
      L.A1F[idx] = (__bf16)v;
    }
    // ---- prep W2F hi/lo: B[k=e_local][col=c=l&15] ----
    for (int it = 0; it < 10; ++it) {
      int idx = it * 1024 + tid;  // 0..10239
      int s = idx & 7, l = (idx >> 3) & 63, rest = idx >> 9;  // 0..19
      int plane = (rest >= 10) ? 1 : 0;
      int cpl = rest - plane * 10;
      int gg = l >> 4;
      int k = (s < 4) ? (4 * gg + s) : (16 + 4 * gg + (s - 4));
      int e = (hh * 10 + cpl) * 32 + k;
      float w = (e < E1OUT) ? W_e2[e * 16 + (l & 15)] : 0.0f;
      __bf16 hi = (__bf16)w;
      if (plane) L.W2Fl[cpl * 512 + (idx & 511)] = (__bf16)(w - (float)hi);
      else       L.W2Fh[cpl * 512 + (idx & 511)] = hi;
    }
    __syncthreads();

#pragma unroll 1
    for (int cpl = 0; cpl < 10; ++cpl) {
      int e0 = (hh * 10 + cpl) * 32;
      // S gather for edge er at e = e0+4g+j (lo) and e0+16+4g+j (hi)
      float4 sa = *(const float4*)(arow + e0 + 4 * g);
      float4 sb = *(const float4*)(brow + e0 + 4 * g);
      float4 sc = *(const float4*)(arow + e0 + 16 + 4 * g);
      float4 sd = *(const float4*)(brow + e0 + 16 + 4 * g);
      bf16x8 a1a = *(const bf16x8*)&L.A1F[(cpl * 2 + 0) * 512 + lane * 8];
      bf16x8 a1b = *(const bf16x8*)&L.A1F[(cpl * 2 + 1) * 512 + lane * 8];
      f32x4 c1a = mfma16(a1a, dfB, zero4);  // C1[e=e0+4g+r][edge=er]
      f32x4 c1b = mfma16(a1b, dfB, zero4);  // C1[e=e0+16+4g+r][edge=er]
      bf16x8 a2;
#pragma unroll
      for (int r = 0; r < 4; ++r) {
        int eA = e0 + 4 * g + r;
        float hA = ((const float*)&sa)[r] + ((const float*)&sb)[r] + c1a[r];
        a2[r] = (__bf16)((eA < E1OUT) ? siluf(hA) : 0.0f);
        int eB = e0 + 16 + 4 * g + r;
        float hB = ((const float*)&sc)[r] + ((const float*)&sd)[r] + c1b[r];
        a2[4 + r] = (__bf16)((eB < E1OUT) ? siluf(hB) : 0.0f);
      }
      bf16x8 w2h = *(const bf16x8*)&L.W2Fh[cpl * 512 + lane * 8];
      bf16x8 w2l = *(const bf16x8*)&L.W2Fl[cpl * 512 + lane * 8];
      zacc = mfma16(a2, w2h, zacc);
      zacc = mfma16(a2, w2l, zacc);
    }
  }

  // epilogue: lane holds z[edge = 4g+r][c = er]
  float bc = b_e2[er];
#pragma unroll
  for (int r = 0; r < 4; ++r) {
    int Eo = Ebase + 4 * g + r;
    int io = Eo / 10;
    float m = siluf(zacc[r] + bc);
    atomicAdd(&m_i[(size_t)io * 16 + er], m);
  }
}

// ---------------------------------------------------------------------------
// LayerNorm + concat m_i -> node_in[32768][160]  (unchanged)
// ---------------------------------------------------------------------------
__global__ __launch_bounds__(256) void node_prep(const float* __restrict__ feats,
                                                 const float* __restrict__ m_i,
                                                 const float* __restrict__ ln_g,
                                                 const float* __restrict__ ln_b,
                                                 float* __restrict__ node_in) {
  int wave = threadIdx.x >> 6, lane = threadIdx.x & 63;
  int i = blockIdx.x * 4 + wave;
  const float* fr = feats + (size_t)i * DD;
  float x0 = fr[lane];
  float x1 = fr[lane + 64];
  float x2 = (lane < 14) ? fr[lane + 128] : 0.0f;
  float s = x0 + x1 + x2;
#pragma unroll
  for (int off = 32; off >= 1; off >>= 1) s += __shfl_xor(s, off, 64);
  float mu = s / 142.0f;
  float d0 = x0 - mu, d1 = x1 - mu, d2 = (lane < 14) ? (x2 - mu) : 0.0f;
  float ss = d0 * d0 + d1 * d1 + d2 * d2;
#pragma unroll
  for (int off = 32; off >= 1; off >>= 1) ss += __shfl_xor(ss, off, 64);
  float var = ss / 142.0f;
  float rstd = 1.0f / sqrtf(var + 1e-5f);
  float* o = node_in + (size_t)i * 160;
  o[lane] = d0 * rstd * ln_g[lane] + ln_b[lane];
  o[lane + 64] = d1 * rstd * ln_g[lane + 64] + ln_b[lane + 64];
  if (lane < 14) o[lane + 128] = d2 * rstd * ln_g[lane + 128] + ln_b[lane + 128];
  if (lane < 16) o[142 + lane] = m_i[i * 16 + lane];
}

// ---------------------------------------------------------------------------
// Masked mean pool fused with head -> f32 emb accumulator (unchanged)
// ---------------------------------------------------------------------------
__global__ __launch_bounds__(256) void pool_kernel(const float* __restrict__ node_out,
                                                   const float* __restrict__ W_out,
                                                   const float* __restrict__ b_out,
                                                   float* __restrict__ emb) {
  int b = blockIdx.x, chunk = blockIdx.y;
  int d = threadIdx.x;
  float acc = 0.0f;
  if (d < DD) {
    const float* base = node_out + ((size_t)(b * NN + chunk * 256)) * 144 + d;
    for (int n = 0; n < 256; ++n) acc += base[(size_t)n * 144];
    acc = acc * W_out[d] * (1.0f / 2048.0f);
  }
  __shared__ float red[256];
  red[threadIdx.x] = acc;
  __syncthreads();
  for (int off = 128; off >= 1; off >>= 1) {
    if (threadIdx.x < off) red[threadIdx.x] += red[threadIdx.x + off];
    __syncthreads();
  }
  if (threadIdx.x == 0) {
    float v = red[0];
    if (chunk == 0) v += b_out[0];
    atomicAdd(&emb[b], v);
  }
}

__global__ void finalize_kernel(const float* __restrict__ emb, float* __restrict__ outp) {
  int t = threadIdx.x;
  if (t < NB) outp[t] = emb[t];
}

// ---------------------------------------------------------------------------
extern "C" void kernel_launch(void* const* d_in, const int* in_sizes, int n_in,
                              void* d_out, int out_size, void* d_ws, size_t ws_size,
                              hipStream_t stream) {
  const float* feats = (const float*)d_in[0];
  const float* coors = (const float*)d_in[1];
  const float* W_e1 = (const float*)d_in[3];
  const float* b_e1 = (const float*)d_in[4];
  const float* W_e2 = (const float*)d_in[5];
  const float* b_e2 = (const float*)d_in[6];
  const float* ln_g = (const float*)d_in[11];
  const float* ln_b = (const float*)d_in[12];
  const float* W_n1 = (const float*)d_in[13];
  const float* b_n1 = (const float*)d_in[14];
  const float* W_n2 = (const float*)d_in[15];
  const float* b_n2 = (const float*)d_in[16];
  const float* W_out = (const float*)d_in[17];
  const float* b_out = (const float*)d_in[18];
  float* out = (float*)d_out;

  char* ws = (char*)d_ws;
  const size_t OFF_IDX = 0;
  const size_t OFF_DIST = 1310720;
  const size_t OFF_MI = 2621440;
  const size_t OFF_AP = 4718592;
  const size_t OFF_BM = 88604672;
  const size_t OFF_NIN = OFF_AP;              // reuse after edge kernel
  const size_t OFF_HN = OFF_AP + 20971520;
  const size_t OFF_NOUT = OFF_HN + 37748736;
  const size_t OFF_EMB = 172490752;

  int* idx = (int*)(ws + OFF_IDX);
  float* dist = (float*)(ws + OFF_DIST);
  float* m_i = (float*)(ws + OFF_MI);
  float* Ap = (float*)(ws + OFF_AP);
  float* Bm = (float*)(ws + OFF_BM);
  float* node_in = (float*)(ws + OFF_NIN);
  float* hnode = (float*)(ws + OFF_HN);
  float* node_out = (float*)(ws + OFF_NOUT);
  float* emb = (float*)(ws + OFF_EMB);

  hipMemsetAsync(m_i, 0, (size_t)NNODES * 16 * 4, stream);
  hipMemsetAsync(emb, 0, (size_t)NB * 4, stream);

  knn_kernel<<<dim3(NB * 512), dim3(256), 0, stream>>>(coors, idx, dist);

  // Ap/Bm via MFMA gemm, xs=2 (feats hi/lo) + ws=2 (weights hi/lo)
  gemm_kernel<<<dim3(10, 512), dim3(256), 0, stream>>>(
      feats, DD, DD, W_e1, E1OUT, 0, E1OUT, b_e1, nullptr, 0, Ap, APITCH, 0, 2, 2);
  gemm_kernel<<<dim3(10, 512), dim3(256), 0, stream>>>(
      feats, DD, DD, W_e1, E1OUT, 142, E1OUT, nullptr, nullptr, 0, Bm, APITCH, 0, 2, 2);

  edge_v8<<<dim3(NEDGES / 256), dim3(1024), 0, stream>>>(
      Ap, Bm, idx, dist, W_e1, W_e2, b_e2, m_i);

  node_prep<<<dim3(NNODES / 4), dim3(256), 0, stream>>>(feats, m_i, ln_g, ln_b, node_in);

  brute_lin<<<dim3(NNODES / 8), dim3(256), 0, stream>>>(
      node_in, 160, 158, W_n1, 284, 0, 284, b_n1, nullptr, 0, hnode, 288, 1);
  brute_lin<<<dim3(NNODES / 8), dim3(256), 0, stream>>>(
      hnode, 288, 284, W_n2, DD, 0, DD, b_n2, feats, DD, node_out, 144, 0);

  pool_kernel<<<dim3(NB, 8), dim3(256), 0, stream>>>(node_out, W_out, b_out, emb);

  finalize_kernel<<<dim3(1), dim3(64), 0, stream>>>(emb, out);
}

// Round 16
// 1112.344 us; speedup vs baseline: 1.0010x; 1.0010x over previous
//
#include <hip/hip_runtime.h>

// ---------------------------------------------------------------------------
// EGNN scoring model, MI355X (gfx950).
// R14: (a) edge_v8 — MFMA edge kernel. R13 proved the edge op is L1-BW-bound
// on shared-weight re-reads; v8 moves weights to LDS frags (40KB, half-
// resident) and the h-dot + z-reduction onto the matrix pipe. Per wave =
// 16 edges; z in one f32x4 accumulator; C1-MFMA C/D layout provably matches
// the z-MFMA A-layout (same mapping as the R12-proven gemm_kernel).
// (b) gemm1 xs=1 -> xs=2: R13 absmax 0.0078125 was 1 display-ULP from the
// 0.00785 threshold; feats hi/lo split restores margin.
// ---------------------------------------------------------------------------

typedef unsigned int u32;
typedef unsigned long long u64;
typedef float f32x4 __attribute__((ext_vector_type(4)));
typedef __bf16 bf16x4 __attribute__((ext_vector_type(4)));
typedef __bf16 bf16x8 __attribute__((ext_vector_type(8)));

#define NB 16
#define NN 2048
#define DD 142
#define KNNK 10
#define NNODES (NB * NN)        // 32768
#define NEDGES (NNODES * KNNK)  // 327680
#define E1OUT 610
#define APITCH 640

__device__ __forceinline__ f32x4 mfma16(bf16x8 a, bf16x8 b, f32x4 c) {
  return __builtin_amdgcn_mfma_f32_16x16x32_bf16(a, b, c, 0, 0, 0);
}
__device__ __forceinline__ float siluf(float x) { return x / (1.0f + __expf(-x)); }

__device__ __forceinline__ u64 wave_min_u64(u64 v) {
#pragma unroll
  for (int off = 32; off >= 1; off >>= 1) {
    u32 lo = (u32)v, hi = (u32)(v >> 32);
    u32 olo = (u32)__shfl_xor((int)lo, off, 64);
    u32 ohi = (u32)__shfl_xor((int)hi, off, 64);
    u64 o = ((u64)ohi << 32) | (u64)olo;
    v = (o < v) ? o : v;
  }
  return v;
}

__device__ __forceinline__ bf16x8 ldfrag40(const __bf16* p) {
  bf16x4 lo = *(const bf16x4*)p;
  bf16x4 hi = *(const bf16x4*)(p + 16);
  return __builtin_shufflevector(lo, hi, 0, 1, 2, 3, 4, 5, 6, 7);
}

// ---------------------------------------------------------------------------
// Wave-parallel KNN (proven, unchanged).
// ---------------------------------------------------------------------------
__global__ __launch_bounds__(256) void knn_kernel(const float* __restrict__ coors,
                                                  int* __restrict__ idxo,
                                                  float* __restrict__ disto) {
  __shared__ float cl[NN * 3];
  int b = blockIdx.x >> 9;
  int i0 = (blockIdx.x & 511) << 2;
  for (int t = threadIdx.x; t < NN * 3; t += 256) cl[t] = coors[b * NN * 3 + t];
  __syncthreads();
  int wave = threadIdx.x >> 6, lane = threadIdx.x & 63;
  int il = i0 + wave;
  float xi = cl[il * 3 + 0], yi = cl[il * 3 + 1], zi = cl[il * 3 + 2];
  u64 r[KNNK];
#pragma unroll
  for (int t = 0; t < KNNK; ++t) r[t] = ~0ull;
  for (int j0 = 0; j0 < NN; j0 += 64) {
    int j = j0 + lane;
    float dx = __fadd_rn(xi, -cl[j * 3 + 0]);
    float dy = __fadd_rn(yi, -cl[j * 3 + 1]);
    float dz = __fadd_rn(zi, -cl[j * 3 + 2]);
    float d2 = __fadd_rn(__fadd_rn(__fmul_rn(dx, dx), __fmul_rn(dy, dy)), __fmul_rn(dz, dz));
    u64 cand = ((u64)__float_as_uint(d2) << 32) | (u64)(u32)j;
    if (cand < r[KNNK - 1]) {
      r[KNNK - 1] = cand;
#pragma unroll
      for (int t = KNNK - 1; t > 0; --t) {
        if (r[t] < r[t - 1]) { u64 tmp = r[t - 1]; r[t - 1] = r[t]; r[t] = tmp; }
      }
    }
  }
  int gi = b * NN + il;
#pragma unroll
  for (int t = 0; t < KNNK; ++t) {
    u64 head = r[0];
    u64 m = wave_min_u64(head);
    if (lane == t) {
      idxo[(size_t)gi * KNNK + t] = b * NN + (int)(u32)(m & 0xffffffffu);
      disto[(size_t)gi * KNNK + t] = __uint_as_float((u32)(m >> 32));
    }
    if (head == m) {
#pragma unroll
      for (int q = 0; q < KNNK - 1; ++q) r[q] = r[q + 1];
      r[KNNK - 1] = ~0ull;
    }
  }
}

// ---------------------------------------------------------------------------
// bf16-MFMA GEMM (proven R12; now xs=2 for feats hi/lo margin).
// ---------------------------------------------------------------------------
__global__ __launch_bounds__(256) void gemm_kernel(
    const float* __restrict__ X, int ldx, int K,
    const float* __restrict__ W, int ldw, int r0, int Ncols,
    const float* __restrict__ bias, const float* __restrict__ resid, int ldr,
    float* __restrict__ C, int ldc, int doSilu, int xs, int ws) {
  __shared__ __bf16 Xs[2][64 * 40];
  __shared__ __bf16 Ws[2][64 * 40];
  int m0 = blockIdx.y * 64, n0 = blockIdx.x * 64;
  int tid = threadIdx.x;
  int lane = tid & 63, wv = tid >> 6;
  int g = lane >> 4, rr = lane & 15;
  f32x4 acc[4];
#pragma unroll
  for (int ct = 0; ct < 4; ++ct) acc[ct] = (f32x4){0.f, 0.f, 0.f, 0.f};
  int nk = (K + 31) >> 5;
  int rs = tid >> 2, q = tid & 3;
  for (int kc = 0; kc < nk; ++kc) {
    int k0 = kc << 5;
#pragma unroll
    for (int u = 0; u < 8; ++u) {
      int kk = q * 8 + u;
      int k = k0 + kk;
      float xv = (k < K) ? X[(size_t)(m0 + rs) * ldx + k] : 0.0f;
      __bf16 xh = (__bf16)xv;
      Xs[0][rs * 40 + kk] = xh;
      if (xs == 2) Xs[1][rs * 40 + kk] = (__bf16)(xv - (float)xh);
      float wvv = (k < K && (n0 + rs) < Ncols) ? W[(size_t)(r0 + k) * ldw + n0 + rs] : 0.0f;
      __bf16 wh = (__bf16)wvv;
      Ws[0][rs * 40 + kk] = wh;
      if (ws == 2) Ws[1][rs * 40 + kk] = (__bf16)(wvv - (float)wh);
    }
    __syncthreads();
    for (int ix = 0; ix < xs; ++ix) {
      bf16x8 a = ldfrag40(&Xs[ix][(16 * wv + rr) * 40 + 4 * g]);
      for (int iw = 0; iw < ws; ++iw) {
#pragma unroll
        for (int ct = 0; ct < 4; ++ct) {
          bf16x8 bb = ldfrag40(&Ws[iw][(16 * ct + rr) * 40 + 4 * g]);
          acc[ct] = mfma16(a, bb, acc[ct]);
        }
      }
    }
    __syncthreads();
  }
#pragma unroll
  for (int ct = 0; ct < 4; ++ct) {
#pragma unroll
    for (int r = 0; r < 4; ++r) {
      int row = m0 + 16 * wv + 4 * g + r;
      int col = n0 + 16 * ct + rr;
      if (col < Ncols) {
        float v = acc[ct][r];
        if (bias) v += bias[col];
        if (doSilu) v = siluf(v);
        if (resid) v += resid[(size_t)row * ldr + col];
        C[(size_t)row * ldc + col] = v;
      }
    }
  }
}

// ---------------------------------------------------------------------------
// Brute linear (proven; node MLP).
// ---------------------------------------------------------------------------
__global__ __launch_bounds__(256) void brute_lin(
    const float* __restrict__ X, int ldx, int K,
    const float* __restrict__ W, int ldw, int r0, int Ncols,
    const float* __restrict__ bias, const float* __restrict__ resid, int ldr,
    float* __restrict__ Y, int ldy, int doSilu) {
  __shared__ float Xs[8 * 284];
  int n0 = blockIdx.x * 8;
  int tid = threadIdx.x;
  for (int p = tid; p < 8 * K; p += 256) {
    int n = p / K, k = p - n * K;
    Xs[n * K + k] = X[(size_t)(n0 + n) * ldx + k];
  }
  __syncthreads();
  float acc[8][3];
#pragma unroll
  for (int n = 0; n < 8; ++n)
#pragma unroll
    for (int s = 0; s < 3; ++s) acc[n][s] = 0.0f;
  int e1 = tid + 256, e2 = tid + 512;
  for (int k = 0; k < K; ++k) {
    const float* wr = W + (size_t)(r0 + k) * ldw;
    float w0 = (tid < Ncols) ? wr[tid] : 0.0f;
    float w1 = (e1 < Ncols) ? wr[e1] : 0.0f;
    float w2 = (e2 < Ncols) ? wr[e2] : 0.0f;
#pragma unroll
    for (int n = 0; n < 8; ++n) {
      float xv = Xs[n * K + k];
      acc[n][0] += xv * w0;
      acc[n][1] += xv * w1;
      acc[n][2] += xv * w2;
    }
  }
#pragma unroll
  for (int n = 0; n < 8; ++n) {
#pragma unroll
    for (int s = 0; s < 3; ++s) {
      int e = tid + s * 256;
      if (e < Ncols) {
        float v = acc[n][s];
        if (bias) v += bias[e];
        if (doSilu) v = siluf(v);
        if (resid) v += resid[(size_t)(n0 + n) * ldr + e];
        Y[(size_t)(n0 + n) * ldy + e] = v;
      }
    }
  }
}

// ---------------------------------------------------------------------------
// Edge kernel v8 (MFMA). 1024 threads = 16 waves; each wave owns 16 edges.
// LDS: pre-swizzled WdT A-frags + W_e2 hi/lo B-frags, half-resident (40KB).
// Per 32-e chunk: S = Ap+Bm gather (4x float4); C1 = WdT@DF (2 MFMA, C/D
// layout == S layout == next A layout); h=S+C1; silu -> a2 frag;
// z += a2 @ W_e2 (hi+lo MFMA). Epilogue: silu(z+b) -> 4 atomics/lane.
// ---------------------------------------------------------------------------
struct EdgeV8Lds {
  __bf16 A1F[20 * 512];   // WdT frags for current half: (cpl*2+sb)*512 + l*8+s
  __bf16 W2Fh[10 * 512];  // W_e2 hi frags
  __bf16 W2Fl[10 * 512];  // W_e2 lo frags
};  // 40960 B

__global__ __launch_bounds__(1024) void edge_v8(
    const float* __restrict__ Ap, const float* __restrict__ Bmm,
    const int* __restrict__ idxE, const float* __restrict__ distE,
    const float* __restrict__ W_e1, const float* __restrict__ W_e2,
    const float* __restrict__ b_e2, float* __restrict__ m_i) {
  __shared__ EdgeV8Lds L;
  int tid = threadIdx.x;
  int wave = tid >> 6, lane = tid & 63;
  int g = lane >> 4, er = lane & 15;
  int tile = blockIdx.x * 16 + wave;  // 1280 blocks * 16 waves = 20480 tiles
  int Ebase = tile * 16;

  // meta for this lane's frag edge (er)
  int Ee = Ebase + er;
  int iE = Ee / 10;
  int jE = idxE[Ee];
  float d2 = distE[Ee];

  // df B-frag: slot s -> t = s<4 ? 4g+s : 16+4g+(s-4); same t<->row map as
  // the proven edge kernels (sin rows 284.., cos 294.., raw 304).
  bf16x8 dfB;
#pragma unroll
  for (int s = 0; s < 8; ++s) {
    int t = (s < 4) ? (4 * g + s) : (16 + 4 * g + (s - 4));
    float v = 0.0f;
    if (t < 10) v = sinf(d2 / (float)(1 << t));
    else if (t < 20) v = cosf(d2 / (float)(1 << (t - 10)));
    else if (t == 20) v = d2;
    dfB[s] = (__bf16)v;
  }

  const float* arow = Ap + (size_t)iE * APITCH;
  const float* brow = Bmm + (size_t)jE * APITCH;

  f32x4 zacc = {0.f, 0.f, 0.f, 0.f};
  f32x4 zero4 = {0.f, 0.f, 0.f, 0.f};

#pragma unroll 1
  for (int hh = 0; hh < 2; ++hh) {
    if (hh) __syncthreads();  // all waves done reading previous half
    // ---- prep A1F: WdT[e][t] frags; A[row=e_local=l&15][k=t] ----
    for (int it = 0; it < 10; ++it) {
      int idx = it * 1024 + tid;  // 0..10239
      int s = idx & 7, l = (idx >> 3) & 63, fid = idx >> 9;  // fid 0..19
      int gg = l >> 4;
      int t = (s < 4) ? (4 * gg + s) : (16 + 4 * gg + (s - 4));
      int e = (hh * 10 + (fid >> 1)) * 32 + (fid & 1) * 16 + (l & 15);
      float v = (t < 21 && e < E1OUT) ? W_e1[(284 + t) * E1OUT + e] : 0.0f;
      L.A1F[idx] = (__bf16)v;
    }
    // ---- prep W2F hi/lo: B[k=e_local][col=c=l&15] ----
    for (int it = 0; it < 10; ++it) {
      int idx = it * 1024 + tid;  // 0..10239
      int s = idx & 7, l = (idx >> 3) & 63, rest = idx >> 9;  // 0..19
      int plane = (rest >= 10) ? 1 : 0;
      int cpl = rest - plane * 10;
      int gg = l >> 4;
      int k = (s < 4) ? (4 * gg + s) : (16 + 4 * gg + (s - 4));
      int e = (hh * 10 + cpl) * 32 + k;
      float w = (e < E1OUT) ? W_e2[e * 16 + (l & 15)] : 0.0f;
      __bf16 hi = (__bf16)w;
      if (plane) L.W2Fl[cpl * 512 + (idx & 511)] = (__bf16)(w - (float)hi);
      else       L.W2Fh[cpl * 512 + (idx & 511)] = hi;
    }
    __syncthreads();

#pragma unroll 1
    for (int cpl = 0; cpl < 10; ++cpl) {
      int e0 = (hh * 10 + cpl) * 32;
      // S gather for edge er at e = e0+4g+j (lo) and e0+16+4g+j (hi)
      float4 sa = *(const float4*)(arow + e0 + 4 * g);
      float4 sb = *(const float4*)(brow + e0 + 4 * g);
      float4 sc = *(const float4*)(arow + e0 + 16 + 4 * g);
      float4 sd = *(const float4*)(brow + e0 + 16 + 4 * g);
      bf16x8 a1a = *(const bf16x8*)&L.A1F[(cpl * 2 + 0) * 512 + lane * 8];
      bf16x8 a1b = *(const bf16x8*)&L.A1F[(cpl * 2 + 1) * 512 + lane * 8];
      f32x4 c1a = mfma16(a1a, dfB, zero4);  // C1[e=e0+4g+r][edge=er]
      f32x4 c1b = mfma16(a1b, dfB, zero4);  // C1[e=e0+16+4g+r][edge=er]
      bf16x8 a2;
#pragma unroll
      for (int r = 0; r < 4; ++r) {
        int eA = e0 + 4 * g + r;
        float hA = ((const float*)&sa)[r] + ((const float*)&sb)[r] + c1a[r];
        a2[r] = (__bf16)((eA < E1OUT) ? siluf(hA) : 0.0f);
        int eB = e0 + 16 + 4 * g + r;
        float hB = ((const float*)&sc)[r] + ((const float*)&sd)[r] + c1b[r];
        a2[4 + r] = (__bf16)((eB < E1OUT) ? siluf(hB) : 0.0f);
      }
      bf16x8 w2h = *(const bf16x8*)&L.W2Fh[cpl * 512 + lane * 8];
      bf16x8 w2l = *(const bf16x8*)&L.W2Fl[cpl * 512 + lane * 8];
      zacc = mfma16(a2, w2h, zacc);
      zacc = mfma16(a2, w2l, zacc);
    }
  }

  // epilogue: lane holds z[edge = 4g+r][c = er]
  float bc = b_e2[er];
#pragma unroll
  for (int r = 0; r < 4; ++r) {
    int Eo = Ebase + 4 * g + r;
    int io = Eo / 10;
    float m = siluf(zacc[r] + bc);
    atomicAdd(&m_i[(size_t)io * 16 + er], m);
  }
}

// ---------------------------------------------------------------------------
// LayerNorm + concat m_i -> node_in[32768][160]  (unchanged)
// ---------------------------------------------------------------------------
__global__ __launch_bounds__(256) void node_prep(const float* __restrict__ feats,
                                                 const float* __restrict__ m_i,
                                                 const float* __restrict__ ln_g,
                                                 const float* __restrict__ ln_b,
                                                 float* __restrict__ node_in) {
  int wave = threadIdx.x >> 6, lane = threadIdx.x & 63;
  int i = blockIdx.x * 4 + wave;
  const float* fr = feats + (size_t)i * DD;
  float x0 = fr[lane];
  float x1 = fr[lane + 64];
  float x2 = (lane < 14) ? fr[lane + 128] : 0.0f;
  float s = x0 + x1 + x2;
#pragma unroll
  for (int off = 32; off >= 1; off >>= 1) s += __shfl_xor(s, off, 64);
  float mu = s / 142.0f;
  float d0 = x0 - mu, d1 = x1 - mu, d2 = (lane < 14) ? (x2 - mu) : 0.0f;
  float ss = d0 * d0 + d1 * d1 + d2 * d2;
#pragma unroll
  for (int off = 32; off >= 1; off >>= 1) ss += __shfl_xor(ss, off, 64);
  float var = ss / 142.0f;
  float rstd = 1.0f / sqrtf(var + 1e-5f);
  float* o = node_in + (size_t)i * 160;
  o[lane] = d0 * rstd * ln_g[lane] + ln_b[lane];
  o[lane + 64] = d1 * rstd * ln_g[lane + 64] + ln_b[lane + 64];
  if (lane < 14) o[lane + 128] = d2 * rstd * ln_g[lane + 128] + ln_b[lane + 128];
  if (lane < 16) o[142 + lane] = m_i[i * 16 + lane];
}

// ---------------------------------------------------------------------------
// Masked mean pool fused with head -> f32 emb accumulator (unchanged)
// ---------------------------------------------------------------------------
__global__ __launch_bounds__(256) void pool_kernel(const float* __restrict__ node_out,
                                                   const float* __restrict__ W_out,
                                                   const float* __restrict__ b_out,
                                                   float* __restrict__ emb) {
  int b = blockIdx.x, chunk = blockIdx.y;
  int d = threadIdx.x;
  float acc = 0.0f;
  if (d < DD) {
    const float* base = node_out + ((size_t)(b * NN + chunk * 256)) * 144 + d;
    for (int n = 0; n < 256; ++n) acc += base[(size_t)n * 144];
    acc = acc * W_out[d] * (1.0f / 2048.0f);
  }
  __shared__ float red[256];
  red[threadIdx.x] = acc;
  __syncthreads();
  for (int off = 128; off >= 1; off >>= 1) {
    if (threadIdx.x < off) red[threadIdx.x] += red[threadIdx.x + off];
    __syncthreads();
  }
  if (threadIdx.x == 0) {
    float v = red[0];
    if (chunk == 0) v += b_out[0];
    atomicAdd(&emb[b], v);
  }
}

__global__ void finalize_kernel(const float* __restrict__ emb, float* __restrict__ outp) {
  int t = threadIdx.x;
  if (t < NB) outp[t] = emb[t];
}

// ---------------------------------------------------------------------------
extern "C" void kernel_launch(void* const* d_in, const int* in_sizes, int n_in,
                              void* d_out, int out_size, void* d_ws, size_t ws_size,
                              hipStream_t stream) {
  const float* feats = (const float*)d_in[0];
  const float* coors = (const float*)d_in[1];
  const float* W_e1 = (const float*)d_in[3];
  const float* b_e1 = (const float*)d_in[4];
  const float* W_e2 = (const float*)d_in[5];
  const float* b_e2 = (const float*)d_in[6];
  const float* ln_g = (const float*)d_in[11];
  const float* ln_b = (const float*)d_in[12];
  const float* W_n1 = (const float*)d_in[13];
  const float* b_n1 = (const float*)d_in[14];
  const float* W_n2 = (const float*)d_in[15];
  const float* b_n2 = (const float*)d_in[16];
  const float* W_out = (const float*)d_in[17];
  const float* b_out = (const float*)d_in[18];
  float* out = (float*)d_out;

  char* ws = (char*)d_ws;
  const size_t OFF_IDX = 0;
  const size_t OFF_DIST = 1310720;
  const size_t OFF_MI = 2621440;
  const size_t OFF_AP = 4718592;
  const size_t OFF_BM = 88604672;
  const size_t OFF_NIN = OFF_AP;              // reuse after edge kernel
  const size_t OFF_HN = OFF_AP + 20971520;
  const size_t OFF_NOUT = OFF_HN + 37748736;
  const size_t OFF_EMB = 172490752;

  int* idx = (int*)(ws + OFF_IDX);
  float* dist = (float*)(ws + OFF_DIST);
  float* m_i = (float*)(ws + OFF_MI);
  float* Ap = (float*)(ws + OFF_AP);
  float* Bm = (float*)(ws + OFF_BM);
  float* node_in = (float*)(ws + OFF_NIN);
  float* hnode = (float*)(ws + OFF_HN);
  float* node_out = (float*)(ws + OFF_NOUT);
  float* emb = (float*)(ws + OFF_EMB);

  hipMemsetAsync(m_i, 0, (size_t)NNODES * 16 * 4, stream);
  hipMemsetAsync(emb, 0, (size_t)NB * 4, stream);

  knn_kernel<<<dim3(NB * 512), dim3(256), 0, stream>>>(coors, idx, dist);

  // Ap/Bm via MFMA gemm, xs=2 (feats hi/lo) + ws=2 (weights hi/lo)
  gemm_kernel<<<dim3(10, 512), dim3(256), 0, stream>>>(
      feats, DD, DD, W_e1, E1OUT, 0, E1OUT, b_e1, nullptr, 0, Ap, APITCH, 0, 2, 2);
  gemm_kernel<<<dim3(10, 512), dim3(256), 0, stream>>>(
      feats, DD, DD, W_e1, E1OUT, 142, E1OUT, nullptr, nullptr, 0, Bm, APITCH, 0, 2, 2);

  edge_v8<<<dim3(NEDGES / 256), dim3(1024), 0, stream>>>(
      Ap, Bm, idx, dist, W_e1, W_e2, b_e2, m_i);

  node_prep<<<dim3(NNODES / 4), dim3(256), 0, stream>>>(feats, m_i, ln_g, ln_b, node_in);

  brute_lin<<<dim3(NNODES / 8), dim3(256), 0, stream>>>(
      node_in, 160, 158, W_n1, 284, 0, 284, b_n1, nullptr, 0, hnode, 288, 1);
  brute_lin<<<dim3(NNODES / 8), dim3(256), 0, stream>>>(
      hnode, 288, 284, W_n2, DD, 0, DD, b_n2, feats, DD, node_out, 144, 0);

  pool_kernel<<<dim3(NB, 8), dim3(256), 0, stream>>>(node_out, W_out, b_out, emb);

  finalize_kernel<<<dim3(1), dim3(64), 0, stream>>>(emb, out);
}